// Round 4
// baseline (95.440 us; speedup 1.0000x reference)
//
#include <hip/hip_runtime.h>
#include <cmath>

namespace {

constexpr int BATCH  = 32;
constexpr int NPOSE  = 2048;
constexpr int KSAMP  = 32;             // samples per segment
constexpr int NSEG   = NPOSE - 1;      // 2047 segments
constexpr int NDELTA = NPOSE + 1;      // 2049 deltas (i = 0..2048)
constexpr int SEGB   = 32;             // segments per block (256 thr x 4 poses)
constexpr float EPS  = 1e-6f;
constexpr float EPS2 = 1e-12f;
constexpr float INV_TWO_PI = 0.15915494309189535f;

struct V3 { float x, y, z; };
struct Q4 { float x, y, z, w; };
struct SE3 { V3 t; Q4 q; };

// hardware-rate math; v_sin/v_cos take revolutions, our angles <= 2pi
__device__ __forceinline__ float frcp(float x)  { return __builtin_amdgcn_rcpf(x); }
__device__ __forceinline__ float fsqrt(float x) { return __builtin_amdgcn_sqrtf(x); }
__device__ __forceinline__ float fsin(float x)  { return __builtin_amdgcn_sinf(x * INV_TWO_PI); }
__device__ __forceinline__ float fcos(float x)  { return __builtin_amdgcn_cosf(x * INV_TWO_PI); }

__device__ __forceinline__ V3 v3add(V3 a, V3 b) { return {a.x + b.x, a.y + b.y, a.z + b.z}; }
__device__ __forceinline__ V3 v3sub(V3 a, V3 b) { return {a.x - b.x, a.y - b.y, a.z - b.z}; }
__device__ __forceinline__ V3 v3scl(V3 a, float s) { return {a.x * s, a.y * s, a.z * s}; }
__device__ __forceinline__ float v3dot(V3 a, V3 b) { return a.x * b.x + a.y * b.y + a.z * b.z; }
__device__ __forceinline__ V3 v3cross(V3 a, V3 b) {
    return {a.y * b.z - a.z * b.y, a.z * b.x - a.x * b.z, a.x * b.y - a.y * b.x};
}

__device__ __forceinline__ V3 qrot(Q4 q, V3 v) {
    V3 qv{q.x, q.y, q.z};
    V3 t = v3scl(v3cross(qv, v), 2.0f);
    return v3add(v3add(v, v3scl(t, q.w)), v3cross(qv, t));
}

__device__ __forceinline__ Q4 qmul(Q4 a, Q4 b) {
    return {a.w * b.x + a.x * b.w + a.y * b.z - a.z * b.y,
            a.w * b.y + a.y * b.w + a.z * b.x - a.x * b.z,
            a.w * b.z + a.z * b.w + a.x * b.y - a.y * b.x,
            a.w * b.w - a.x * b.x - a.y * b.y - a.z * b.z};
}

__device__ __forceinline__ SE3 se3_mul(SE3 A, SE3 Bv) {
    SE3 r;
    r.t = v3add(A.t, qrot(A.q, Bv.t));
    r.q = qmul(A.q, Bv.q);
    return r;
}

// fast acos, |err| <~ 7e-5 rad; for unit quats atan2(|qv|, w) == acos(w)
__device__ __forceinline__ float facos(float x) {
    float ax = fabsf(x);
    float p = -0.0012624911f;
    p = p * ax + 0.0066700901f;
    p = p * ax - 0.0170881256f;
    p = p * ax + 0.0308918810f;
    p = p * ax - 0.0501743046f;
    p = p * ax + 0.0889789874f;
    p = p * ax - 0.2145988016f;
    p = p * ax + 1.5707963050f;
    float r = fsqrt(fmaxf(1.0f - ax, 0.0f)) * p;
    return (x >= 0.0f) ? r : (3.14159265358979f - r);
}

__device__ __forceinline__ V3 so3_log(Q4 q) {
    V3 qv{q.x, q.y, q.z};
    float n2 = v3dot(qv, qv);
    bool small = n2 < EPS2;
    float n = fsqrt(small ? 1.0f : n2);
    float iw = frcp(q.w);
    float f_small = 2.0f * iw - (2.0f / 3.0f) * n2 * iw * iw * iw;
    float wc = fminf(fmaxf(q.w, -1.0f), 1.0f);
    float f_big = 2.0f * facos(wc) * frcp(n);
    return v3scl(qv, small ? f_small : f_big);
}

__device__ __forceinline__ V3 jl_inv(V3 phi, V3 v) {
    float t2 = v3dot(phi, phi);
    bool small = t2 < EPS2;
    float t2s = small ? 1.0f : t2;
    float theta = fsqrt(t2s);
    float s = fsin(theta), cth = fcos(theta);
    float s_safe = (fabsf(s) < EPS) ? EPS : s;
    float c_big = frcp(t2s) - (1.0f + cth) * frcp(2.0f * theta * s_safe);
    float c = small ? (1.0f / 12.0f + t2 * (1.0f / 720.0f)) : c_big;
    V3 c1 = v3cross(phi, v);
    return v3add(v3sub(v, v3scl(c1, 0.5f)), v3scl(v3cross(phi, c1), c));
}

// ---------------- Kernel 1: per-delta precompute ----------------
// delta i = se3_log(inv(padded(i)) * padded(i+1)), padded(j)=input[clamp(j-1,0,N-1)]
// Row (4 x float4): [tau, nphi] [uhat, 0] [c1 = uhat x tau, 0] [c2 = uhat x c1, 0]
__global__ __launch_bounds__(256) void lie_delta_kernel(
    const float* __restrict__ poses,   // [B, N, 7]
    float4* __restrict__ ws)           // [B, NDELTA, 4] float4
{
    const int i = blockIdx.x * 256 + threadIdx.x;
    const int b = blockIdx.y;
    if (i >= NDELTA) return;

    int ia = max(i - 1, 0);
    int ib = min(i, NPOSE - 1);
    const float* Pa = poses + ((size_t)b * NPOSE + ia) * 7;
    const float* Pb = poses + ((size_t)b * NPOSE + ib) * 7;
    V3 ta{Pa[0], Pa[1], Pa[2]}; Q4 qa{Pa[3], Pa[4], Pa[5], Pa[6]};
    V3 tb{Pb[0], Pb[1], Pb[2]}; Q4 qb{Pb[3], Pb[4], Pb[5], Pb[6]};

    Q4 qi{-qa.x, -qa.y, -qa.z, qa.w};
    V3 trel = qrot(qi, v3sub(tb, ta));
    Q4 qrel = qmul(qi, qb);
    V3 phi = so3_log(qrel);
    V3 tau = jl_inv(phi, trel);

    float n2 = v3dot(phi, phi);
    float nphi = fsqrt(n2);
    float inv_n = frcp(fmaxf(nphi, 1e-20f));   // phi==0 -> uhat=0 -> c1=c2=0
    V3 u  = v3scl(phi, inv_n);
    V3 c1 = v3cross(u, tau);
    V3 c2 = v3cross(u, c1);

    float4* row = ws + ((size_t)b * NDELTA + i) * 4;
    row[0] = make_float4(tau.x, tau.y, tau.z, nphi);
    row[1] = make_float4(u.x,  u.y,  u.z,  0.0f);
    row[2] = make_float4(c1.x, c1.y, c1.z, 0.0f);
    row[3] = make_float4(c2.x, c2.y, c2.z, 0.0f);
}

// exp of w*delta from precomputed row (exact algebra, no small-angle branch;
// identity deltas have c1=c2=u=0 so sA/sB values are irrelevant there)
__device__ __forceinline__ SE3 exp_fast(float4 A, float4 U, float4 C1, float4 C2, float w) {
    float th = fmaxf(w * A.w, 1e-12f);
    float sh = fsin(0.5f * th), ch = fcos(0.5f * th);
    float it = frcp(th);
    float sA = 2.0f * sh * sh * it;              // (1-cos th)/th
    float sB = 1.0f - 2.0f * sh * ch * it;       // 1 - sin(th)/th
    SE3 r;
    r.q = {sh * U.x, sh * U.y, sh * U.z, ch};
    r.t = {w * (A.x + sA * C1.x + sB * C2.x),
           w * (A.y + sA * C1.y + sB * C2.y),
           w * (A.z + sA * C1.z + sB * C2.z)};
    return r;
}

// ---------------- Kernel 2: compose + write ----------------
// Block: 32 segments x 32 k = 1024 outputs; thread = (segment, 4 consecutive k).
// sdel record stride = 5 float4 (80 B) so the 8 distinct per-wave row addresses
// hit disjoint bank quads (stride 4 would 4-way conflict on seg parity).
// Direct global float4 stores: thread's 4 poses = contiguous 112 B, 16B-aligned.
__global__ __launch_bounds__(256) void lie_spline_kernel(
    const float* __restrict__ poses,   // [B, N, 7]
    const float* __restrict__ timev,   // [K]
    const float4* __restrict__ ws,     // [B, NDELTA, 4] float4
    float* __restrict__ out)           // [B, S*K, 7]
{
    __shared__ float4 sdel[(SEGB + 2) * 5];      // 34 records x 4 used of 5
    __shared__ float  sp[SEGB * 8];              // p0 pose per segment (7 of 8)
    __shared__ float  sw[3 * KSAMP];             // w0|w1|w2 per k

    const int b   = blockIdx.y;
    const int s0  = blockIdx.x * SEGB;
    const int tid = threadIdx.x;

    // ---- fill (all coalesced / tiny) ----
    if (tid < (SEGB + 2) * 4) {                  // 136 float4 loads
        int row = tid >> 2, r = tid & 3;
        int idx = min(s0 + row, NDELTA - 1);
        sdel[row * 5 + r] = ws[((size_t)b * NDELTA + idx) * 4 + r];
    }
    if (tid < SEGB * 7) {                        // 224 p0 floats
        int jseg = tid / 7, c = tid - jseg * 7;
        int ip = min(max(s0 + jseg - 1, 0), NPOSE - 1);
        sp[jseg * 8 + c] = poses[((size_t)b * NPOSE + ip) * 7 + c];
    }
    if (tid >= 224) {                            // 32 weight triples
        int l = tid - 224;
        float u = timev[l];
        float u2 = u * u, u3 = u2 * u;
        const float c6 = 1.0f / 6.0f;
        sw[l]             = (5.0f + 3.0f * u - 3.0f * u2 + u3) * c6;
        sw[KSAMP + l]     = (1.0f + 3.0f * u + 3.0f * u2 - 2.0f * u3) * c6;
        sw[2 * KSAMP + l] = u3 * c6;
    }
    __syncthreads();

    const int segl = tid >> 3;                   // 0..31
    const int s    = s0 + segl;
    if (s >= NSEG) return;                       // only tail block, last 8 threads
    const int k0   = (tid & 7) * 4;

    // delta records for segments segl, segl+1, segl+2 (read ONCE per 4 outputs)
    const float4* R0 = sdel + segl * 5;
    const float4* R1 = R0 + 5;
    const float4* R2 = R0 + 10;
    float4 A0 = R0[0], U0 = R0[1], C10 = R0[2], C20 = R0[3];
    float4 A1 = R1[0], U1 = R1[1], C11 = R1[2], C21 = R1[3];
    float4 A2 = R2[0], U2 = R2[1], C12 = R2[2], C22 = R2[3];

    const float* P0 = sp + segl * 8;
    const SE3 Tp{{P0[0], P0[1], P0[2]}, {P0[3], P0[4], P0[5], P0[6]}};

    float buf[4 * 7];
    #pragma unroll
    for (int j = 0; j < 4; ++j) {
        int k = k0 + j;
        float w0 = sw[k], w1 = sw[KSAMP + k], w2 = sw[2 * KSAMP + k];
        SE3 T = se3_mul(Tp, exp_fast(A0, U0, C10, C20, w0));
        T = se3_mul(T, exp_fast(A1, U1, C11, C21, w1));
        T = se3_mul(T, exp_fast(A2, U2, C12, C22, w2));
        float* d = buf + j * 7;
        d[0] = T.t.x; d[1] = T.t.y; d[2] = T.t.z;
        d[3] = T.q.x; d[4] = T.q.y; d[5] = T.q.z; d[6] = T.q.w;
    }

    // thread's 4 poses = 28 contiguous floats; base = ((b*NSEG+s0)*224 + tid*28)
    // floats -> bytes 896*blk + 112*tid, both 16B multiples -> aligned float4
    float4* ov = reinterpret_cast<float4*>(
        out + ((size_t)b * NSEG + s0) * (size_t)(KSAMP * 7) + (size_t)tid * 28);
    #pragma unroll
    for (int c = 0; c < 7; ++c)
        ov[c] = make_float4(buf[4 * c], buf[4 * c + 1], buf[4 * c + 2], buf[4 * c + 3]);
}

} // namespace

extern "C" void kernel_launch(void* const* d_in, const int* in_sizes, int n_in,
                              void* d_out, int out_size, void* d_ws, size_t ws_size,
                              hipStream_t stream) {
    const float* poses = (const float*)d_in[0];   // [32, 2048, 7] fp32
    const float* timev = (const float*)d_in[1];   // [32] fp32
    float* out = (float*)d_out;                   // [32, 2047*32, 7] fp32
    float4* ws = (float4*)d_ws;                   // [32, 2049, 4] float4 = 4.2 MB
    (void)in_sizes; (void)n_in; (void)out_size; (void)ws_size;

    dim3 g1((NDELTA + 255) / 256, BATCH);         // (9, 32)
    lie_delta_kernel<<<g1, 256, 0, stream>>>(poses, ws);

    dim3 g2((NSEG + SEGB - 1) / SEGB, BATCH);     // (64, 32)
    lie_spline_kernel<<<g2, 256, 0, stream>>>(poses, timev, ws, out);
}

// Round 5
// 90.022 us; speedup vs baseline: 1.0602x; 1.0602x over previous
//
#include <hip/hip_runtime.h>
#include <cmath>

namespace {

constexpr int BATCH  = 32;
constexpr int NPOSE  = 2048;
constexpr int KSAMP  = 32;             // samples per segment
constexpr int NSEG   = NPOSE - 1;      // 2047 segments
constexpr int NDELTA = NPOSE + 1;      // 2049 deltas (i = 0..2048)
constexpr int SEGB   = 32;             // segments per block (256 thr x 4 poses)
constexpr float EPS  = 1e-6f;
constexpr float EPS2 = 1e-12f;
constexpr float INV_TWO_PI = 0.15915494309189535f;

struct V3 { float x, y, z; };
struct Q4 { float x, y, z, w; };
struct SE3 { V3 t; Q4 q; };

// hardware-rate math; v_sin/v_cos take revolutions, our angles <= 2pi
__device__ __forceinline__ float frcp(float x)  { return __builtin_amdgcn_rcpf(x); }
__device__ __forceinline__ float fsqrt(float x) { return __builtin_amdgcn_sqrtf(x); }
__device__ __forceinline__ float fsin(float x)  { return __builtin_amdgcn_sinf(x * INV_TWO_PI); }
__device__ __forceinline__ float fcos(float x)  { return __builtin_amdgcn_cosf(x * INV_TWO_PI); }

__device__ __forceinline__ V3 v3add(V3 a, V3 b) { return {a.x + b.x, a.y + b.y, a.z + b.z}; }
__device__ __forceinline__ V3 v3sub(V3 a, V3 b) { return {a.x - b.x, a.y - b.y, a.z - b.z}; }
__device__ __forceinline__ V3 v3scl(V3 a, float s) { return {a.x * s, a.y * s, a.z * s}; }
__device__ __forceinline__ float v3dot(V3 a, V3 b) { return a.x * b.x + a.y * b.y + a.z * b.z; }
__device__ __forceinline__ V3 v3cross(V3 a, V3 b) {
    return {a.y * b.z - a.z * b.y, a.z * b.x - a.x * b.z, a.x * b.y - a.y * b.x};
}

__device__ __forceinline__ V3 qrot(Q4 q, V3 v) {
    V3 qv{q.x, q.y, q.z};
    V3 t = v3scl(v3cross(qv, v), 2.0f);
    return v3add(v3add(v, v3scl(t, q.w)), v3cross(qv, t));
}

__device__ __forceinline__ Q4 qmul(Q4 a, Q4 b) {
    return {a.w * b.x + a.x * b.w + a.y * b.z - a.z * b.y,
            a.w * b.y + a.y * b.w + a.z * b.x - a.x * b.z,
            a.w * b.z + a.z * b.w + a.x * b.y - a.y * b.x,
            a.w * b.w - a.x * b.x - a.y * b.y - a.z * b.z};
}

__device__ __forceinline__ SE3 se3_mul(SE3 A, SE3 Bv) {
    SE3 r;
    r.t = v3add(A.t, qrot(A.q, Bv.t));
    r.q = qmul(A.q, Bv.q);
    return r;
}

// fast acos, |err| <~ 7e-5 rad; for unit quats atan2(|qv|, w) == acos(w)
__device__ __forceinline__ float facos(float x) {
    float ax = fabsf(x);
    float p = -0.0012624911f;
    p = p * ax + 0.0066700901f;
    p = p * ax - 0.0170881256f;
    p = p * ax + 0.0308918810f;
    p = p * ax - 0.0501743046f;
    p = p * ax + 0.0889789874f;
    p = p * ax - 0.2145988016f;
    p = p * ax + 1.5707963050f;
    float r = fsqrt(fmaxf(1.0f - ax, 0.0f)) * p;
    return (x >= 0.0f) ? r : (3.14159265358979f - r);
}

__device__ __forceinline__ V3 so3_log(Q4 q) {
    V3 qv{q.x, q.y, q.z};
    float n2 = v3dot(qv, qv);
    bool small = n2 < EPS2;
    float n = fsqrt(small ? 1.0f : n2);
    float iw = frcp(q.w);
    float f_small = 2.0f * iw - (2.0f / 3.0f) * n2 * iw * iw * iw;
    float wc = fminf(fmaxf(q.w, -1.0f), 1.0f);
    float f_big = 2.0f * facos(wc) * frcp(n);
    return v3scl(qv, small ? f_small : f_big);
}

__device__ __forceinline__ V3 jl_inv(V3 phi, V3 v) {
    float t2 = v3dot(phi, phi);
    bool small = t2 < EPS2;
    float t2s = small ? 1.0f : t2;
    float theta = fsqrt(t2s);
    float s = fsin(theta), cth = fcos(theta);
    float s_safe = (fabsf(s) < EPS) ? EPS : s;
    float c_big = frcp(t2s) - (1.0f + cth) * frcp(2.0f * theta * s_safe);
    float c = small ? (1.0f / 12.0f + t2 * (1.0f / 720.0f)) : c_big;
    V3 c1 = v3cross(phi, v);
    return v3add(v3sub(v, v3scl(c1, 0.5f)), v3scl(v3cross(phi, c1), c));
}

// ---------------- Kernel 1: per-delta precompute ----------------
// delta i = se3_log(inv(padded(i)) * padded(i+1)), padded(j)=input[clamp(j-1,0,N-1)]
// Row (4 x float4): [tau, nphi] [uhat, 0] [c1 = uhat x tau, 0] [c2 = uhat x c1, 0]
__global__ __launch_bounds__(256) void lie_delta_kernel(
    const float* __restrict__ poses,   // [B, N, 7]
    float4* __restrict__ ws)           // [B, NDELTA, 4] float4
{
    const int i = blockIdx.x * 256 + threadIdx.x;
    const int b = blockIdx.y;
    if (i >= NDELTA) return;

    int ia = max(i - 1, 0);
    int ib = min(i, NPOSE - 1);
    const float* Pa = poses + ((size_t)b * NPOSE + ia) * 7;
    const float* Pb = poses + ((size_t)b * NPOSE + ib) * 7;
    V3 ta{Pa[0], Pa[1], Pa[2]}; Q4 qa{Pa[3], Pa[4], Pa[5], Pa[6]};
    V3 tb{Pb[0], Pb[1], Pb[2]}; Q4 qb{Pb[3], Pb[4], Pb[5], Pb[6]};

    Q4 qi{-qa.x, -qa.y, -qa.z, qa.w};
    V3 trel = qrot(qi, v3sub(tb, ta));
    Q4 qrel = qmul(qi, qb);
    V3 phi = so3_log(qrel);
    V3 tau = jl_inv(phi, trel);

    float n2 = v3dot(phi, phi);
    float nphi = fsqrt(n2);
    float inv_n = frcp(fmaxf(nphi, 1e-20f));   // phi==0 -> uhat=0 -> c1=c2=0
    V3 u  = v3scl(phi, inv_n);
    V3 c1 = v3cross(u, tau);
    V3 c2 = v3cross(u, c1);

    float4* row = ws + ((size_t)b * NDELTA + i) * 4;
    row[0] = make_float4(tau.x, tau.y, tau.z, nphi);
    row[1] = make_float4(u.x,  u.y,  u.z,  0.0f);
    row[2] = make_float4(c1.x, c1.y, c1.z, 0.0f);
    row[3] = make_float4(c2.x, c2.y, c2.z, 0.0f);
}

// exp of w*delta from precomputed row (exact algebra, no small-angle branch;
// identity deltas have c1=c2=u=0 so sA/sB values are irrelevant there).
// Verified passing in rounds 3-4 (absmax 0.0625) — do not perturb.
__device__ __forceinline__ SE3 exp_fast(float4 A, float4 U, float4 C1, float4 C2, float w) {
    float th = fmaxf(w * A.w, 1e-12f);
    float sh = fsin(0.5f * th), ch = fcos(0.5f * th);
    float it = frcp(th);
    float sA = 2.0f * sh * sh * it;              // (1-cos th)/th
    float sB = 1.0f - 2.0f * sh * ch * it;       // 1 - sin(th)/th
    SE3 r;
    r.q = {sh * U.x, sh * U.y, sh * U.z, ch};
    r.t = {w * (A.x + sA * C1.x + sB * C2.x),
           w * (A.y + sA * C1.y + sB * C2.y),
           w * (A.z + sA * C1.z + sB * C2.z)};
    return r;
}

// ---------------- Kernel 2: compose + write ----------------
// Block: 32 segments x 32 k = 1024 outputs; thread = (segment, 4 consecutive k).
// Compute amortized in registers (12 ds_read_b128 per 4 outputs); stores routed
// through a 28 KB LDS stage so the global write is pure stride-1 float4
// (round-4's direct 112B-strided stores cost ~4x line-request amplification).
// sdel record stride = 5 float4 so the 8 per-wave row addresses spread banks.
__global__ __launch_bounds__(256) void lie_spline_kernel(
    const float* __restrict__ poses,   // [B, N, 7]
    const float* __restrict__ timev,   // [K]
    const float4* __restrict__ ws,     // [B, NDELTA, 4] float4
    float* __restrict__ out)           // [B, S*K, 7]
{
    __shared__ float4 sdel[(SEGB + 2) * 5];              // 2720 B
    __shared__ __align__(16) float stage[SEGB * KSAMP * 7];  // 28672 B

    const int b   = blockIdx.y;
    const int s0  = blockIdx.x * SEGB;
    const int tid = threadIdx.x;

    // ---- fill sdel (coalesced 16 B loads) ----
    if (tid < (SEGB + 2) * 4) {                  // 136 float4
        int row = tid >> 2, r = tid & 3;
        int idx = min(s0 + row, NDELTA - 1);
        sdel[row * 5 + r] = ws[((size_t)b * NDELTA + idx) * 4 + r];
    }

    const int segl = tid >> 3;                   // 0..31
    const int s    = s0 + segl;
    const int m    = tid & 7;                    // k-quad index

    // p0 pose: direct global read (8-way shared row, L1-hot); issue pre-barrier
    int ip = min(max(s - 1, 0), NPOSE - 1);
    const float* P0 = poses + ((size_t)b * NPOSE + ip) * 7;
    const SE3 Tp{{P0[0], P0[1], P0[2]}, {P0[3], P0[4], P0[5], P0[6]}};
    // 4 time samples for this thread (timev = 32 floats = 8 float4)
    float4 uvec = reinterpret_cast<const float4*>(timev)[m];

    __syncthreads();

    // delta records for segments segl, segl+1, segl+2 (read ONCE per 4 outputs)
    const float4* R = sdel + segl * 5;
    float4 A0 = R[0],  U0 = R[1],  C10 = R[2],  C20 = R[3];
    float4 A1 = R[5],  U1 = R[6],  C11 = R[7],  C21 = R[8];
    float4 A2 = R[10], U2 = R[11], C12 = R[12], C22 = R[13];

    __align__(16) float buf[28];                 // 4 poses, output order
    const float us[4] = {uvec.x, uvec.y, uvec.z, uvec.w};
    #pragma unroll
    for (int j = 0; j < 4; ++j) {
        float u  = us[j];
        float u2 = u * u, u3 = u2 * u;
        const float c6 = 1.0f / 6.0f;
        float w0 = (5.0f + 3.0f * u - 3.0f * u2 + u3) * c6;
        float w1 = (1.0f + 3.0f * u + 3.0f * u2 - 2.0f * u3) * c6;
        float w2 = u3 * c6;
        SE3 T = se3_mul(Tp, exp_fast(A0, U0, C10, C20, w0));
        T = se3_mul(T, exp_fast(A1, U1, C11, C21, w1));
        T = se3_mul(T, exp_fast(A2, U2, C12, C22, w2));
        float* d = buf + j * 7;
        d[0] = T.t.x; d[1] = T.t.y; d[2] = T.t.z;
        d[3] = T.q.x; d[4] = T.q.y; d[5] = T.q.z; d[6] = T.q.w;
    }

    // stage: thread's 28 floats are output-contiguous -> 7 ds_write_b128
    // (byte addr = 896*segl + 112*m -> 16B aligned; per-8-lane group the bank
    // quads (7m+c) mod 8 are distinct -> conflict-free)
    if (s < NSEG) {
        float4* sv = reinterpret_cast<float4*>(stage + segl * (KSAMP * 7) + m * 28);
        const float4* bv = reinterpret_cast<const float4*>(buf);
        #pragma unroll
        for (int c = 0; c < 7; ++c) sv[c] = bv[c];
    }
    __syncthreads();

    // ---- pure stride-1 float4 copy of the block's contiguous output slab ----
    int nseg_blk = min(NSEG - s0, SEGB);
    int nvec = nseg_blk * (KSAMP * 7 / 4);       // 1792 (tail: 1736)
    const float4* svv = reinterpret_cast<const float4*>(stage);
    float4* ov = reinterpret_cast<float4*>(out + ((size_t)b * NSEG + s0) * (size_t)(KSAMP * 7));
    for (int j = tid; j < nvec; j += 256) ov[j] = svv[j];
}

} // namespace

extern "C" void kernel_launch(void* const* d_in, const int* in_sizes, int n_in,
                              void* d_out, int out_size, void* d_ws, size_t ws_size,
                              hipStream_t stream) {
    const float* poses = (const float*)d_in[0];   // [32, 2048, 7] fp32
    const float* timev = (const float*)d_in[1];   // [32] fp32
    float* out = (float*)d_out;                   // [32, 2047*32, 7] fp32
    float4* ws = (float4*)d_ws;                   // [32, 2049, 4] float4 = 4.2 MB
    (void)in_sizes; (void)n_in; (void)out_size; (void)ws_size;

    dim3 g1((NDELTA + 255) / 256, BATCH);         // (9, 32)
    lie_delta_kernel<<<g1, 256, 0, stream>>>(poses, ws);

    dim3 g2((NSEG + SEGB - 1) / SEGB, BATCH);     // (64, 32)
    lie_spline_kernel<<<g2, 256, 0, stream>>>(poses, timev, ws, out);
}

// Round 6
// 87.469 us; speedup vs baseline: 1.0911x; 1.0292x over previous
//
#include <hip/hip_runtime.h>
#include <cmath>

namespace {

constexpr int BATCH  = 32;
constexpr int NPOSE  = 2048;
constexpr int KSAMP  = 32;             // samples per segment
constexpr int NSEG   = NPOSE - 1;      // 2047 segments
constexpr int NDELTA = NPOSE + 1;      // 2049 deltas (i = 0..2048)
constexpr int SEGB   = 32;             // segments per block (256 thr x 4 poses)
constexpr float EPS  = 1e-6f;
constexpr float EPS2 = 1e-12f;
constexpr float INV_TWO_PI = 0.15915494309189535f;

struct V3 { float x, y, z; };
struct Q4 { float x, y, z, w; };
struct SE3 { V3 t; Q4 q; };

// hardware-rate math; v_sin/v_cos take revolutions, our angles <= 2pi
__device__ __forceinline__ float frcp(float x)  { return __builtin_amdgcn_rcpf(x); }
__device__ __forceinline__ float fsqrt(float x) { return __builtin_amdgcn_sqrtf(x); }
__device__ __forceinline__ float fsin(float x)  { return __builtin_amdgcn_sinf(x * INV_TWO_PI); }
__device__ __forceinline__ float fcos(float x)  { return __builtin_amdgcn_cosf(x * INV_TWO_PI); }

__device__ __forceinline__ V3 v3add(V3 a, V3 b) { return {a.x + b.x, a.y + b.y, a.z + b.z}; }
__device__ __forceinline__ V3 v3sub(V3 a, V3 b) { return {a.x - b.x, a.y - b.y, a.z - b.z}; }
__device__ __forceinline__ V3 v3scl(V3 a, float s) { return {a.x * s, a.y * s, a.z * s}; }
__device__ __forceinline__ float v3dot(V3 a, V3 b) { return a.x * b.x + a.y * b.y + a.z * b.z; }
__device__ __forceinline__ V3 v3cross(V3 a, V3 b) {
    return {a.y * b.z - a.z * b.y, a.z * b.x - a.x * b.z, a.x * b.y - a.y * b.x};
}

__device__ __forceinline__ V3 qrot(Q4 q, V3 v) {
    V3 qv{q.x, q.y, q.z};
    V3 t = v3scl(v3cross(qv, v), 2.0f);
    return v3add(v3add(v, v3scl(t, q.w)), v3cross(qv, t));
}

__device__ __forceinline__ Q4 qmul(Q4 a, Q4 b) {
    return {a.w * b.x + a.x * b.w + a.y * b.z - a.z * b.y,
            a.w * b.y + a.y * b.w + a.z * b.x - a.x * b.z,
            a.w * b.z + a.z * b.w + a.x * b.y - a.y * b.x,
            a.w * b.w - a.x * b.x - a.y * b.y - a.z * b.z};
}

__device__ __forceinline__ SE3 se3_mul(SE3 A, SE3 Bv) {
    SE3 r;
    r.t = v3add(A.t, qrot(A.q, Bv.t));
    r.q = qmul(A.q, Bv.q);
    return r;
}

// fast acos, |err| <~ 7e-5 rad; for unit quats atan2(|qv|, w) == acos(w)
__device__ __forceinline__ float facos(float x) {
    float ax = fabsf(x);
    float p = -0.0012624911f;
    p = p * ax + 0.0066700901f;
    p = p * ax - 0.0170881256f;
    p = p * ax + 0.0308918810f;
    p = p * ax - 0.0501743046f;
    p = p * ax + 0.0889789874f;
    p = p * ax - 0.2145988016f;
    p = p * ax + 1.5707963050f;
    float r = fsqrt(fmaxf(1.0f - ax, 0.0f)) * p;
    return (x >= 0.0f) ? r : (3.14159265358979f - r);
}

__device__ __forceinline__ V3 so3_log(Q4 q) {
    V3 qv{q.x, q.y, q.z};
    float n2 = v3dot(qv, qv);
    bool small = n2 < EPS2;
    float n = fsqrt(small ? 1.0f : n2);
    float iw = frcp(q.w);
    float f_small = 2.0f * iw - (2.0f / 3.0f) * n2 * iw * iw * iw;
    float wc = fminf(fmaxf(q.w, -1.0f), 1.0f);
    float f_big = 2.0f * facos(wc) * frcp(n);
    return v3scl(qv, small ? f_small : f_big);
}

__device__ __forceinline__ V3 jl_inv(V3 phi, V3 v) {
    float t2 = v3dot(phi, phi);
    bool small = t2 < EPS2;
    float t2s = small ? 1.0f : t2;
    float theta = fsqrt(t2s);
    float s = fsin(theta), cth = fcos(theta);
    float s_safe = (fabsf(s) < EPS) ? EPS : s;
    float c_big = frcp(t2s) - (1.0f + cth) * frcp(2.0f * theta * s_safe);
    float c = small ? (1.0f / 12.0f + t2 * (1.0f / 720.0f)) : c_big;
    V3 c1 = v3cross(phi, v);
    return v3add(v3sub(v, v3scl(c1, 0.5f)), v3scl(v3cross(phi, c1), c));
}

// exp of w*delta from precomputed record (exact algebra; verified rounds 3-5)
__device__ __forceinline__ SE3 exp_fast(float4 A, float4 U, float4 C1, float4 C2, float w) {
    float th = fmaxf(w * A.w, 1e-12f);
    float sh = fsin(0.5f * th), ch = fcos(0.5f * th);
    float it = frcp(th);
    float sA = 2.0f * sh * sh * it;              // (1-cos th)/th
    float sB = 1.0f - 2.0f * sh * ch * it;       // 1 - sin(th)/th
    SE3 r;
    r.q = {sh * U.x, sh * U.y, sh * U.z, ch};
    r.t = {w * (A.x + sA * C1.x + sB * C2.x),
           w * (A.y + sA * C1.y + sB * C2.y),
           w * (A.z + sA * C1.z + sB * C2.z)};
    return r;
}

// ---------------- single fused kernel ----------------
// Block: 32 segments x 32 k = 1024 outputs; thread = (segment, 4 consecutive k).
// Phase A: threads 0..33 compute the block's 34 delta records -> LDS
//          (6% duplicated work vs a dedicated kernel, but no 8.4 MB ws
//           round-trip and no second launch; imbalance hidden by 5 blocks/CU).
// Phase B: per-thread 4 poses, ALL state in named registers (no local arrays
//          anywhere -> nothing can be demoted to scratch).
// Phase C: LDS stage -> pure stride-1 float4 global copy (R4 showed direct
//          112B-strided stores cost ~4x line amplification on 57 MB).
__global__ __launch_bounds__(256) void lie_spline_fused(
    const float* __restrict__ poses,   // [B, N, 7]
    const float* __restrict__ timev,   // [K]
    float* __restrict__ out)           // [B, S*K, 7]
{
    __shared__ float4 sdel[(SEGB + 2) * 5];                  // 2720 B, stride-5 records
    __shared__ __align__(16) float stage[SEGB * KSAMP * 7];  // 28672 B

    const int b   = blockIdx.y;
    const int s0  = blockIdx.x * SEGB;
    const int tid = threadIdx.x;

    const int segl = tid >> 3;                   // 0..31
    const int m    = tid & 7;                    // k-quad index
    const int s    = s0 + segl;

    // per-thread p0 pose + time quad (issued pre-barrier; 8-way shared rows, L1-hot)
    int ip = min(max(s - 1, 0), NPOSE - 1);
    const float* P0 = poses + ((size_t)b * NPOSE + ip) * 7;
    const SE3 Tp{{P0[0], P0[1], P0[2]}, {P0[3], P0[4], P0[5], P0[6]}};
    const float4 uvec = reinterpret_cast<const float4*>(timev)[m];

    // ---- Phase A: delta records for indices s0 .. s0+33 ----
    if (tid < SEGB + 2) {
        int i = min(s0 + tid, NDELTA - 1);       // clamp only affects unused tail record
        int ia = max(i - 1, 0);
        int ib = min(i, NPOSE - 1);
        const float* Pa = poses + ((size_t)b * NPOSE + ia) * 7;
        const float* Pb = poses + ((size_t)b * NPOSE + ib) * 7;
        V3 ta{Pa[0], Pa[1], Pa[2]}; Q4 qa{Pa[3], Pa[4], Pa[5], Pa[6]};
        V3 tb{Pb[0], Pb[1], Pb[2]}; Q4 qb{Pb[3], Pb[4], Pb[5], Pb[6]};

        Q4 qi{-qa.x, -qa.y, -qa.z, qa.w};
        V3 trel = qrot(qi, v3sub(tb, ta));
        Q4 qrel = qmul(qi, qb);
        V3 phi = so3_log(qrel);
        V3 tau = jl_inv(phi, trel);

        float nphi = fsqrt(v3dot(phi, phi));
        float inv_n = frcp(fmaxf(nphi, 1e-20f)); // phi==0 -> uhat=0 -> c1=c2=0
        V3 u  = v3scl(phi, inv_n);
        V3 c1 = v3cross(u, tau);
        V3 c2 = v3cross(u, c1);

        float4* r = sdel + tid * 5;
        r[0] = make_float4(tau.x, tau.y, tau.z, nphi);
        r[1] = make_float4(u.x,  u.y,  u.z,  0.0f);
        r[2] = make_float4(c1.x, c1.y, c1.z, 0.0f);
        r[3] = make_float4(c2.x, c2.y, c2.z, 0.0f);
    }
    __syncthreads();

    // ---- Phase B: 4 poses in named registers ----
    if (s < NSEG) {
        const float4* R = sdel + segl * 5;
        const float4 A0 = R[0],  U0 = R[1],  C10 = R[2],  C20 = R[3];
        const float4 A1 = R[5],  U1 = R[6],  C11 = R[7],  C21 = R[8];
        const float4 A2 = R[10], U2 = R[11], C12 = R[12], C22 = R[13];

        const float c6 = 1.0f / 6.0f;
        SE3 T0, T1, T2, T3;
        #define POSE_AT(u_, Tdst_)                                              \
        {                                                                       \
            float u = (u_);                                                     \
            float u2 = u * u, u3 = u2 * u;                                      \
            float w0 = (5.0f + 3.0f * u - 3.0f * u2 + u3) * c6;                 \
            float w1 = (1.0f + 3.0f * u + 3.0f * u2 - 2.0f * u3) * c6;          \
            float w2 = u3 * c6;                                                 \
            SE3 T = se3_mul(Tp, exp_fast(A0, U0, C10, C20, w0));                \
            T = se3_mul(T, exp_fast(A1, U1, C11, C21, w1));                     \
            T = se3_mul(T, exp_fast(A2, U2, C12, C22, w2));                     \
            Tdst_ = T;                                                          \
        }
        POSE_AT(uvec.x, T0)
        POSE_AT(uvec.y, T1)
        POSE_AT(uvec.z, T2)
        POSE_AT(uvec.w, T3)
        #undef POSE_AT

        // stage the thread's 28 output-contiguous floats as 7 explicit float4s
        // (byte addr 896*segl + 112*m -> 16B aligned; bank quads (7m+c) mod 8
        // distinct within each 8-lane group -> conflict-free)
        float4* sv = reinterpret_cast<float4*>(stage + segl * (KSAMP * 7) + m * 28);
        sv[0] = make_float4(T0.t.x, T0.t.y, T0.t.z, T0.q.x);
        sv[1] = make_float4(T0.q.y, T0.q.z, T0.q.w, T1.t.x);
        sv[2] = make_float4(T1.t.y, T1.t.z, T1.q.x, T1.q.y);
        sv[3] = make_float4(T1.q.z, T1.q.w, T2.t.x, T2.t.y);
        sv[4] = make_float4(T2.t.z, T2.q.x, T2.q.y, T2.q.z);
        sv[5] = make_float4(T2.q.w, T3.t.x, T3.t.y, T3.t.z);
        sv[6] = make_float4(T3.q.x, T3.q.y, T3.q.z, T3.q.w);
    }
    __syncthreads();

    // ---- Phase C: pure stride-1 float4 copy of the contiguous output slab ----
    int nseg_blk = min(NSEG - s0, SEGB);
    int nvec = nseg_blk * (KSAMP * 7 / 4);       // 1792 (tail: 1736)
    const float4* svv = reinterpret_cast<const float4*>(stage);
    float4* ov = reinterpret_cast<float4*>(out + ((size_t)b * NSEG + s0) * (size_t)(KSAMP * 7));
    for (int j = tid; j < nvec; j += 256) ov[j] = svv[j];
}

} // namespace

extern "C" void kernel_launch(void* const* d_in, const int* in_sizes, int n_in,
                              void* d_out, int out_size, void* d_ws, size_t ws_size,
                              hipStream_t stream) {
    const float* poses = (const float*)d_in[0];   // [32, 2048, 7] fp32
    const float* timev = (const float*)d_in[1];   // [32] fp32
    float* out = (float*)d_out;                   // [32, 2047*32, 7] fp32
    (void)in_sizes; (void)n_in; (void)out_size; (void)d_ws; (void)ws_size;

    dim3 grid((NSEG + SEGB - 1) / SEGB, BATCH);   // (64, 32)
    lie_spline_fused<<<grid, 256, 0, stream>>>(poses, timev, out);
}

// Round 7
// 79.986 us; speedup vs baseline: 1.1932x; 1.0936x over previous
//
#include <hip/hip_runtime.h>
#include <cmath>

namespace {

typedef _Float16 half_t;
typedef _Float16 h2 __attribute__((ext_vector_type(2)));

constexpr int BATCH  = 32;
constexpr int NPOSE  = 2048;
constexpr int KSAMP  = 32;             // samples per segment
constexpr int NSEG   = NPOSE - 1;      // 2047 segments
constexpr int NDELTA = NPOSE + 1;      // 2049 deltas
constexpr int SEGB   = 32;             // segments per block (256 thr x 4 poses)
constexpr float EPS  = 1e-6f;
constexpr float EPS2 = 1e-12f;
constexpr float INV_TWO_PI = 0.15915494309189535f;

struct V3 { float x, y, z; };
struct Q4 { float x, y, z, w; };
struct SE3 { V3 t; Q4 q; };

__device__ __forceinline__ float frcp(float x)  { return __builtin_amdgcn_rcpf(x); }
__device__ __forceinline__ float fsqrt(float x) { return __builtin_amdgcn_sqrtf(x); }
__device__ __forceinline__ float fsin(float x)  { return __builtin_amdgcn_sinf(x * INV_TWO_PI); }
__device__ __forceinline__ float fcos(float x)  { return __builtin_amdgcn_cosf(x * INV_TWO_PI); }

__device__ __forceinline__ h2 h2pack(float a, float b) { return h2{(half_t)a, (half_t)b}; }
__device__ __forceinline__ h2 h2splat(float a) { half_t h = (half_t)a; return h2{h, h}; }

__device__ __forceinline__ V3 v3add(V3 a, V3 b) { return {a.x + b.x, a.y + b.y, a.z + b.z}; }
__device__ __forceinline__ V3 v3sub(V3 a, V3 b) { return {a.x - b.x, a.y - b.y, a.z - b.z}; }
__device__ __forceinline__ V3 v3scl(V3 a, float s) { return {a.x * s, a.y * s, a.z * s}; }
__device__ __forceinline__ float v3dot(V3 a, V3 b) { return a.x * b.x + a.y * b.y + a.z * b.z; }
__device__ __forceinline__ V3 v3cross(V3 a, V3 b) {
    return {a.y * b.z - a.z * b.y, a.z * b.x - a.x * b.z, a.x * b.y - a.y * b.x};
}

__device__ __forceinline__ V3 qrot(Q4 q, V3 v) {
    V3 qv{q.x, q.y, q.z};
    V3 t = v3scl(v3cross(qv, v), 2.0f);
    return v3add(v3add(v, v3scl(t, q.w)), v3cross(qv, t));
}

__device__ __forceinline__ Q4 qmul(Q4 a, Q4 b) {
    return {a.w * b.x + a.x * b.w + a.y * b.z - a.z * b.y,
            a.w * b.y + a.y * b.w + a.z * b.x - a.x * b.z,
            a.w * b.z + a.z * b.w + a.x * b.y - a.y * b.x,
            a.w * b.w - a.x * b.x - a.y * b.y - a.z * b.z};
}

// fast acos, |err| <~ 7e-5 rad; for unit quats atan2(|qv|, w) == acos(w)
__device__ __forceinline__ float facos(float x) {
    float ax = fabsf(x);
    float p = -0.0012624911f;
    p = p * ax + 0.0066700901f;
    p = p * ax - 0.0170881256f;
    p = p * ax + 0.0308918810f;
    p = p * ax - 0.0501743046f;
    p = p * ax + 0.0889789874f;
    p = p * ax - 0.2145988016f;
    p = p * ax + 1.5707963050f;
    float r = fsqrt(fmaxf(1.0f - ax, 0.0f)) * p;
    return (x >= 0.0f) ? r : (3.14159265358979f - r);
}

__device__ __forceinline__ V3 so3_log(Q4 q) {
    V3 qv{q.x, q.y, q.z};
    float n2 = v3dot(qv, qv);
    bool small = n2 < EPS2;
    float n = fsqrt(small ? 1.0f : n2);
    float iw = frcp(q.w);
    float f_small = 2.0f * iw - (2.0f / 3.0f) * n2 * iw * iw * iw;
    float wc = fminf(fmaxf(q.w, -1.0f), 1.0f);
    float f_big = 2.0f * facos(wc) * frcp(n);
    return v3scl(qv, small ? f_small : f_big);
}

__device__ __forceinline__ V3 jl_inv(V3 phi, V3 v) {
    float t2 = v3dot(phi, phi);
    bool small = t2 < EPS2;
    float t2s = small ? 1.0f : t2;
    float theta = fsqrt(t2s);
    float s = fsin(theta), cth = fcos(theta);
    float s_safe = (fabsf(s) < EPS) ? EPS : s;
    float c_big = frcp(t2s) - (1.0f + cth) * frcp(2.0f * theta * s_safe);
    float c = small ? (1.0f / 12.0f + t2 * (1.0f / 720.0f)) : c_big;
    V3 c1 = v3cross(phi, v);
    return v3add(v3sub(v, v3scl(c1, 0.5f)), v3scl(v3cross(phi, c1), c));
}

// ---- packed-fp16 SE(3) over 2 k-samples (halves of each h2) ----
struct V3h { h2 x, y, z; };
struct Q4h { h2 x, y, z, w; };
struct SE3h { V3h t; Q4h q; };

__device__ __forceinline__ SE3h se3_mul_h(const SE3h& A, const SE3h& B) {
    h2 cx = A.q.y * B.t.z - A.q.z * B.t.y;
    h2 cy = A.q.z * B.t.x - A.q.x * B.t.z;
    h2 cz = A.q.x * B.t.y - A.q.y * B.t.x;
    cx = cx + cx; cy = cy + cy; cz = cz + cz;
    SE3h r;
    r.t.x = A.t.x + B.t.x + A.q.w * cx + (A.q.y * cz - A.q.z * cy);
    r.t.y = A.t.y + B.t.y + A.q.w * cy + (A.q.z * cx - A.q.x * cz);
    r.t.z = A.t.z + B.t.z + A.q.w * cz + (A.q.x * cy - A.q.y * cx);
    r.q.x = A.q.w * B.q.x + A.q.x * B.q.w + A.q.y * B.q.z - A.q.z * B.q.y;
    r.q.y = A.q.w * B.q.y + A.q.y * B.q.w + A.q.z * B.q.x - A.q.x * B.q.z;
    r.q.z = A.q.w * B.q.z + A.q.z * B.q.w + A.q.x * B.q.y - A.q.y * B.q.x;
    r.q.w = A.q.w * B.q.w - A.q.x * B.q.x - A.q.y * B.q.y - A.q.z * B.q.z;
    return r;
}

// E(w*delta) for two k's. Coefficients in fp32 (handles identity deltas exactly:
// sa==0 -> cA=cB=0 even with inv_n=1e20), vector math packed fp16.
// Equivalence with verified R3-R6 form: w*sA = (1-cos th)/n = cA, w*sB = (th - sin th)/n = cB.
__device__ __forceinline__ SE3h build_E(const float4& A, const float4& U,
                                        const float4& C1, const float4& C2,
                                        float wa, float wb) {
    const float inv_n = U.w;                   // per-delta 1/nphi (0-safe via exact-zero sa)
    float tha = wa * A.w, thb = wb * A.w;      // th = w * nphi
    float sa = fsin(0.5f * tha), ca = fcos(0.5f * tha);
    float sb = fsin(0.5f * thb), cb = fcos(0.5f * thb);
    float cAa = 2.0f * sa * sa * inv_n;        // (1 - cos th)/n
    float cAb = 2.0f * sb * sb * inv_n;
    float cBa = (tha - 2.0f * sa * ca) * inv_n; // (th - sin th)/n
    float cBb = (thb - 2.0f * sb * cb) * inv_n;
    h2 s2 = h2pack(sa, sb), c2 = h2pack(ca, cb);
    h2 cA = h2pack(cAa, cAb), cB = h2pack(cBa, cBb), wh = h2pack(wa, wb);
    SE3h E;
    E.q.x = s2 * h2splat(U.x); E.q.y = s2 * h2splat(U.y); E.q.z = s2 * h2splat(U.z);
    E.q.w = c2;
    E.t.x = wh * h2splat(A.x) + cA * h2splat(C1.x) + cB * h2splat(C2.x);
    E.t.y = wh * h2splat(A.y) + cA * h2splat(C1.y) + cB * h2splat(C2.y);
    E.t.z = wh * h2splat(A.z) + cA * h2splat(C1.z) + cB * h2splat(C2.z);
    return E;
}

// ---------------- single fused kernel ----------------
// Phase A: threads 0..33 -> 34 delta records in LDS (fp32, unchanged math;
//          record now stores inv_n in U.w).
// Phase B: thread = (segment, 4 k's as 2 fp16-packed pairs); compose in
//          v_pk_*_f16 (2 poses per instruction, zero swizzle — k is elementwise).
// Phase C: LDS stage -> pure stride-1 float4 global copy.
__global__ __launch_bounds__(256) void lie_spline_fused(
    const float* __restrict__ poses,   // [B, N, 7]
    const float* __restrict__ timev,   // [K]
    float* __restrict__ out)           // [B, S*K, 7]
{
    __shared__ float4 sdel[(SEGB + 2) * 5];                  // stride-5 records
    __shared__ __align__(16) float stage[SEGB * KSAMP * 7];  // 28672 B

    const int b   = blockIdx.y;
    const int s0  = blockIdx.x * SEGB;
    const int tid = threadIdx.x;

    const int segl = tid >> 3;                   // 0..31
    const int m    = tid & 7;                    // k-quad index
    const int s    = s0 + segl;

    int ip = min(max(s - 1, 0), NPOSE - 1);
    const float* P0 = poses + ((size_t)b * NPOSE + ip) * 7;
    const float4 uvec = reinterpret_cast<const float4*>(timev)[m];
    // p0 as packed broadcast (both halves identical)
    SE3h Tph;
    Tph.t.x = h2splat(P0[0]); Tph.t.y = h2splat(P0[1]); Tph.t.z = h2splat(P0[2]);
    Tph.q.x = h2splat(P0[3]); Tph.q.y = h2splat(P0[4]); Tph.q.z = h2splat(P0[5]);
    Tph.q.w = h2splat(P0[6]);

    // ---- Phase A ----
    if (tid < SEGB + 2) {
        int i = min(s0 + tid, NDELTA - 1);
        int ia = max(i - 1, 0);
        int ib = min(i, NPOSE - 1);
        const float* Pa = poses + ((size_t)b * NPOSE + ia) * 7;
        const float* Pb = poses + ((size_t)b * NPOSE + ib) * 7;
        V3 ta{Pa[0], Pa[1], Pa[2]}; Q4 qa{Pa[3], Pa[4], Pa[5], Pa[6]};
        V3 tb{Pb[0], Pb[1], Pb[2]}; Q4 qb{Pb[3], Pb[4], Pb[5], Pb[6]};

        Q4 qi{-qa.x, -qa.y, -qa.z, qa.w};
        V3 trel = qrot(qi, v3sub(tb, ta));
        Q4 qrel = qmul(qi, qb);
        V3 phi = so3_log(qrel);
        V3 tau = jl_inv(phi, trel);

        float nphi = fsqrt(v3dot(phi, phi));
        float inv_n = frcp(fmaxf(nphi, 1e-20f)); // identity: phi=0 -> u=c1=c2=0 exactly
        V3 u  = v3scl(phi, inv_n);
        V3 c1 = v3cross(u, tau);
        V3 c2 = v3cross(u, c1);

        float4* r = sdel + tid * 5;
        r[0] = make_float4(tau.x, tau.y, tau.z, nphi);
        r[1] = make_float4(u.x,  u.y,  u.z,  inv_n);
        r[2] = make_float4(c1.x, c1.y, c1.z, 0.0f);
        r[3] = make_float4(c2.x, c2.y, c2.z, 0.0f);
    }
    __syncthreads();

    // ---- Phase B ----
    if (s < NSEG) {
        const float4* R = sdel + segl * 5;
        const float4 A0 = R[0],  U0 = R[1],  C10 = R[2],  C20 = R[3];
        const float4 A1 = R[5],  U1 = R[6],  C11 = R[7],  C21 = R[8];
        const float4 A2 = R[10], U2 = R[11], C12 = R[12], C22 = R[13];

        const float c6 = 1.0f / 6.0f;
        SE3h TA, TB;
        #define POSE_PAIR(ua_, ub_, Tdst_)                                       \
        {                                                                        \
            float ua = (ua_), ub = (ub_);                                        \
            float ua2 = ua * ua, ua3 = ua2 * ua;                                 \
            float ub2 = ub * ub, ub3 = ub2 * ub;                                 \
            float w0a = (5.0f + 3.0f * ua - 3.0f * ua2 + ua3) * c6;              \
            float w0b = (5.0f + 3.0f * ub - 3.0f * ub2 + ub3) * c6;              \
            float w1a = (1.0f + 3.0f * ua + 3.0f * ua2 - 2.0f * ua3) * c6;       \
            float w1b = (1.0f + 3.0f * ub + 3.0f * ub2 - 2.0f * ub3) * c6;       \
            float w2a = ua3 * c6, w2b = ub3 * c6;                                \
            SE3h T = se3_mul_h(Tph, build_E(A0, U0, C10, C20, w0a, w0b));        \
            T = se3_mul_h(T, build_E(A1, U1, C11, C21, w1a, w1b));               \
            T = se3_mul_h(T, build_E(A2, U2, C12, C22, w2a, w2b));               \
            Tdst_ = T;                                                           \
        }
        POSE_PAIR(uvec.x, uvec.y, TA)
        POSE_PAIR(uvec.z, uvec.w, TB)
        #undef POSE_PAIR

        // unpack halves (pose0=TA.lo, pose1=TA.hi, pose2=TB.lo, pose3=TB.hi)
        float4* sv = reinterpret_cast<float4*>(stage + segl * (KSAMP * 7) + m * 28);
        sv[0] = make_float4((float)TA.t.x.x, (float)TA.t.y.x, (float)TA.t.z.x, (float)TA.q.x.x);
        sv[1] = make_float4((float)TA.q.y.x, (float)TA.q.z.x, (float)TA.q.w.x, (float)TA.t.x.y);
        sv[2] = make_float4((float)TA.t.y.y, (float)TA.t.z.y, (float)TA.q.x.y, (float)TA.q.y.y);
        sv[3] = make_float4((float)TA.q.z.y, (float)TA.q.w.y, (float)TB.t.x.x, (float)TB.t.y.x);
        sv[4] = make_float4((float)TB.t.z.x, (float)TB.q.x.x, (float)TB.q.y.x, (float)TB.q.z.x);
        sv[5] = make_float4((float)TB.q.w.x, (float)TB.t.x.y, (float)TB.t.y.y, (float)TB.t.z.y);
        sv[6] = make_float4((float)TB.q.x.y, (float)TB.q.y.y, (float)TB.q.z.y, (float)TB.q.w.y);
    }
    __syncthreads();

    // ---- Phase C ----
    int nseg_blk = min(NSEG - s0, SEGB);
    int nvec = nseg_blk * (KSAMP * 7 / 4);
    const float4* svv = reinterpret_cast<const float4*>(stage);
    float4* ov = reinterpret_cast<float4*>(out + ((size_t)b * NSEG + s0) * (size_t)(KSAMP * 7));
    for (int j = tid; j < nvec; j += 256) ov[j] = svv[j];
}

} // namespace

extern "C" void kernel_launch(void* const* d_in, const int* in_sizes, int n_in,
                              void* d_out, int out_size, void* d_ws, size_t ws_size,
                              hipStream_t stream) {
    const float* poses = (const float*)d_in[0];   // [32, 2048, 7] fp32
    const float* timev = (const float*)d_in[1];   // [32] fp32
    float* out = (float*)d_out;                   // [32, 2047*32, 7] fp32
    (void)in_sizes; (void)n_in; (void)out_size; (void)d_ws; (void)ws_size;

    dim3 grid((NSEG + SEGB - 1) / SEGB, BATCH);   // (64, 32)
    lie_spline_fused<<<grid, 256, 0, stream>>>(poses, timev, out);
}